// Round 2
// baseline (3774.826 us; speedup 1.0000x reference)
//
#include <hip/hip_runtime.h>
#include <hip/hip_fp16.h>
#include <cmath>

#define NN 20000
#define EE 500000
#define GG 64
#define TS 4096
#define EPS 1e-5f

__device__ __forceinline__ float softplus_ref(float x) {
    return fmaxf(x, 0.f) + log1pf(__expf(-fabsf(x)));
}
__device__ __forceinline__ float softplus_fast(float x) {
    return fmaxf(x, 0.f) + __logf(1.0f + __expf(-fabsf(x)));
}
__device__ __forceinline__ float sigmoid_fast(float x) {
    return __builtin_amdgcn_rcpf(1.0f + __expf(-x));
}

// gaussian table: g[s][k] = exp(coeff*(d_s - o_k)^2)
__global__ void k_gtab(float* __restrict__ g) {
    int i = blockIdx.x * 256 + threadIdx.x;
    if (i >= TS * 100) return;
    int s = i / 100, k = i - 100 * s;
    float d = s * (6.0f / 4095.0f);
    float o = k * (6.0f / 99.0f);
    float step = 6.0f / 99.0f;
    float coeff = -0.5f / (step * step);
    float df = d - o;
    g[i] = __expf(coeff * df * df);
}

// Paired layout: Tp[l][s][t] = half2(T[c=t], T[c=t+64])
__global__ void k_build_T(const float* __restrict__ g, const float* __restrict__ convW,
                          const float* __restrict__ convB, __half2* __restrict__ Tp) {
    int t = threadIdx.x;            // 64
    int s = blockIdx.x;             // TS
    int l = blockIdx.y;             // 6
    const float* gr = g + (size_t)s * 100;
    const float* w = convW + ((size_t)l * 228 + 128) * 128;
    float a0 = convB[l * 128 + t];
    float a1 = convB[l * 128 + t + 64];
#pragma unroll 4
    for (int k = 0; k < 100; k++) {
        float gv = gr[k];
        a0 += gv * w[k * 128 + t];
        a1 += gv * w[k * 128 + t + 64];
    }
    Tp[((size_t)l * TS + s) * 64 + t] = __floats2half2_rn(a0, a1);
}

__global__ void k_embed(const int* __restrict__ an, const float* __restrict__ emb,
                        const float* __restrict__ W, const float* __restrict__ b,
                        float* __restrict__ x) {
    int c = threadIdx.x & 63, nl = threadIdx.x >> 6;
    int n = blockIdx.x * 4 + nl;
    if (n >= NN) return;
    const float* e = emb + (size_t)an[n] * 92;
    float acc = b[c];
#pragma unroll 4
    for (int k = 0; k < 92; k++) acc += e[k] * W[k * 64 + c];
    x[(size_t)n * 64 + c] = acc;
}

__global__ void k_hist(const int* __restrict__ dst, int* __restrict__ counts) {
    int e = blockIdx.x * 256 + threadIdx.x;
    if (e < EE) atomicAdd(&counts[dst[e]], 1);
}

__global__ void k_scan(const int* __restrict__ counts, int* __restrict__ rp) {
    __shared__ int buf[1024];
    __shared__ int carry;
    int tid = threadIdx.x;
    if (tid == 0) { carry = 0; rp[0] = 0; }
    __syncthreads();
    for (int base = 0; base < NN; base += 1024) {
        int i = base + tid;
        int val = (i < NN) ? counts[i] : 0;
        buf[tid] = val;
        __syncthreads();
        for (int off = 1; off < 1024; off <<= 1) {
            int t = (tid >= off) ? buf[tid - off] : 0;
            __syncthreads();
            buf[tid] += t;
            __syncthreads();
        }
        if (i < NN) rp[i + 1] = carry + buf[tid];
        __syncthreads();
        if (tid == 0) carry += buf[1023];
        __syncthreads();
    }
}

__global__ void k_scatter(const int* __restrict__ dst, const int* __restrict__ rp,
                          int* __restrict__ cursor, int* __restrict__ perm) {
    int e = blockIdx.x * 256 + threadIdx.x;
    if (e < EE) {
        int d = dst[e];
        int p = atomicAdd(&cursor[d], 1);
        perm[rp[d] + p] = e;
    }
}

// u,v in paired layout: up[n][t] = half2(u_t, u_{t+64})
__global__ void k_uv(const float* __restrict__ x, const float* __restrict__ convW,
                     int l, __half2* __restrict__ up, __half2* __restrict__ vp) {
    int lane = threadIdx.x & 63;
    int n = blockIdx.x * 4 + (threadIdx.x >> 6);
    if (n >= NN) return;
    float xv = x[(size_t)n * 64 + lane];
    const float* W1 = convW + (size_t)l * 228 * 128;          // rows 0..63   (dst half)
    const float* W2 = W1 + (size_t)64 * 128;                  // rows 64..127 (src half)
    float a0 = 0.f, a1 = 0.f, b0 = 0.f, b1 = 0.f;
#pragma unroll 4
    for (int k = 0; k < 64; k++) {
        float xk = __shfl(xv, k, 64);
        const float* r1 = W1 + (size_t)k * 128;
        const float* r2 = W2 + (size_t)k * 128;
        a0 += xk * r1[lane]; a1 += xk * r1[lane + 64];
        b0 += xk * r2[lane]; b1 += xk * r2[lane + 64];
    }
    up[(size_t)n * 64 + lane] = __floats2half2_rn(a0, a1);
    vp[(size_t)n * 64 + lane] = __floats2half2_rn(b0, b1);
}

// pass A: compute z, BN stats, optional z store (perm order)
__global__ void __launch_bounds__(256) k_zstats(
    const __half2* __restrict__ up, const __half2* __restrict__ vp,
    const __half2* __restrict__ Tp,
    const int* __restrict__ src, const float* __restrict__ dist,
    const int* __restrict__ rp, const int* __restrict__ perm,
    float* __restrict__ sums, __half2* __restrict__ zbuf) {
    int i = blockIdx.x;
    int lane = threadIdx.x & 63, slot = threadIdx.x >> 6;
    float2 uu = __half22float2(up[(size_t)i * 64 + lane]);
    float sx = 0.f, sy = 0.f, qx = 0.f, qy = 0.f;
    int rs = rp[i], re = rp[i + 1];
    for (int idx = rs + slot; idx < re; idx += 4) {
        int e = perm[idx];
        int si = src[e];
        float t = dist[e] * (4095.0f / 6.0f);
        int j = (int)t; j = min(j, TS - 2);
        float f = t - (float)j;
        float2 vv = __half22float2(vp[(size_t)si * 64 + lane]);
        float2 t0 = __half22float2(Tp[(size_t)j * 64 + lane]);
        float2 t1 = __half22float2(Tp[(size_t)(j + 1) * 64 + lane]);
        float z0 = uu.x + vv.x + t0.x + (t1.x - t0.x) * f;
        float z1 = uu.y + vv.y + t0.y + (t1.y - t0.y) * f;
        if (zbuf) zbuf[(size_t)idx * 64 + lane] = __floats2half2_rn(z0, z1);
        sx += z0; qx += z0 * z0;
        sy += z1; qy += z1 * z1;
    }
    __shared__ float red[4][64][4];
    red[slot][lane][0] = sx; red[slot][lane][1] = sy;
    red[slot][lane][2] = qx; red[slot][lane][3] = qy;
    __syncthreads();
    if (slot == 0) {
        for (int r = 1; r < 4; r++) {
            sx += red[r][lane][0]; sy += red[r][lane][1];
            qx += red[r][lane][2]; qy += red[r][lane][3];
        }
        atomicAdd(&sums[lane], sx);
        atomicAdd(&sums[lane + 64], sy);
        atomicAdd(&sums[128 + lane], qx);
        atomicAdd(&sums[192 + lane], qy);
    }
}

__global__ void k_finalize(float* __restrict__ sums, const float* __restrict__ bn_g,
                           const float* __restrict__ bn_b, int l, float* __restrict__ AB) {
    int c = threadIdx.x; // 128
    float mu = sums[c] * (1.0f / EE);
    float ms = sums[128 + c] * (1.0f / EE);
    float var = ms - mu * mu;
    float rstd = rsqrtf(var + EPS);
    float A = rstd * bn_g[l * 128 + c];
    float B = bn_b[l * 128 + c] - mu * A;
    AB[c] = A; AB[128 + c] = B;
    sums[c] = 0.f; sums[128 + c] = 0.f;
}

__device__ __forceinline__ void agg_epilogue(float acc, int i, int lane, int slot, int l,
                                             const float* __restrict__ lng,
                                             const float* __restrict__ lnb,
                                             const float* __restrict__ xin,
                                             float* __restrict__ xout) {
    __shared__ float red[4][64];
    red[slot][lane] = acc;
    __syncthreads();
    if (slot == 0) {
        float a = red[0][lane] + red[1][lane] + red[2][lane] + red[3][lane];
        float s = a;
#pragma unroll
        for (int off = 32; off; off >>= 1) s += __shfl_xor(s, off, 64);
        float mean = s * (1.0f / 64.0f);
        float e0 = a - mean;
        float vv = e0 * e0;
#pragma unroll
        for (int off = 32; off; off >>= 1) vv += __shfl_xor(vv, off, 64);
        float var = vv * (1.0f / 64.0f);
        float h = e0 * rsqrtf(var + EPS) * lng[l * 64 + lane] + lnb[l * 64 + lane];
        float xn = h + xin[(size_t)i * 64 + lane];
        xout[(size_t)i * 64 + lane] = softplus_ref(xn);
    }
}

// pass B fast path: stream zbuf
__global__ void __launch_bounds__(256) k_agg_z(
    const __half2* __restrict__ zbuf, const int* __restrict__ rp,
    const float* __restrict__ AB, const float* __restrict__ lng, const float* __restrict__ lnb,
    int l, const float* __restrict__ xin, float* __restrict__ xout) {
    int i = blockIdx.x;
    int lane = threadIdx.x & 63, slot = threadIdx.x >> 6;
    float A1 = AB[lane], A2 = AB[lane + 64];
    float B1 = AB[128 + lane], B2 = AB[128 + lane + 64];
    float acc = 0.f;
    int rs = rp[i], re = rp[i + 1];
    for (int idx = rs + slot; idx < re; idx += 4) {
        float2 z = __half22float2(zbuf[(size_t)idx * 64 + lane]);
        float z1 = z.x * A1 + B1;
        float z2 = z.y * A2 + B2;
        acc += sigmoid_fast(z1) * softplus_fast(z2);
    }
    agg_epilogue(acc, i, lane, slot, l, lng, lnb, xin, xout);
}

// pass B fallback: recompute z
__global__ void __launch_bounds__(256) k_agg_re(
    const __half2* __restrict__ up, const __half2* __restrict__ vp,
    const __half2* __restrict__ Tp,
    const int* __restrict__ src, const float* __restrict__ dist,
    const int* __restrict__ rp, const int* __restrict__ perm,
    const float* __restrict__ AB, const float* __restrict__ lng, const float* __restrict__ lnb,
    int l, const float* __restrict__ xin, float* __restrict__ xout) {
    int i = blockIdx.x;
    int lane = threadIdx.x & 63, slot = threadIdx.x >> 6;
    float2 uu = __half22float2(up[(size_t)i * 64 + lane]);
    float A1 = AB[lane], A2 = AB[lane + 64];
    float B1 = AB[128 + lane], B2 = AB[128 + lane + 64];
    float acc = 0.f;
    int rs = rp[i], re = rp[i + 1];
    for (int idx = rs + slot; idx < re; idx += 4) {
        int e = perm[idx];
        int si = src[e];
        float t = dist[e] * (4095.0f / 6.0f);
        int j = (int)t; j = min(j, TS - 2);
        float f = t - (float)j;
        float2 vv = __half22float2(vp[(size_t)si * 64 + lane]);
        float2 t0 = __half22float2(Tp[(size_t)j * 64 + lane]);
        float2 t1 = __half22float2(Tp[(size_t)(j + 1) * 64 + lane]);
        float z1 = (uu.x + vv.x + t0.x + (t1.x - t0.x) * f) * A1 + B1;
        float z2 = (uu.y + vv.y + t0.y + (t1.y - t0.y) * f) * A2 + B2;
        acc += sigmoid_fast(z1) * softplus_fast(z2);
    }
    agg_epilogue(acc, i, lane, slot, l, lng, lnb, xin, xout);
}

// batch sorted -> graph row pointers by binary search
__global__ void k_gp(const int* __restrict__ batch, int* __restrict__ gp) {
    int g = threadIdx.x;
    if (g > GG) return;
    int lo = 0, hi = NN;
    while (lo < hi) {
        int mid = (lo + hi) >> 1;
        if (batch[mid] < g) lo = mid + 1; else hi = mid;
    }
    gp[g] = lo;
}

// atomic-free segmented mean-pool (writes mean directly)
__global__ void k_pool2(const float* __restrict__ x, const int* __restrict__ gp,
                        float* __restrict__ mols) {
    int g = blockIdx.x;
    int lane = threadIdx.x & 63, slot = threadIdx.x >> 6;
    int s0 = gp[g], s1 = gp[g + 1];
    float acc = 0.f;
    for (int n = s0 + slot; n < s1; n += 4) acc += x[(size_t)n * 64 + lane];
    __shared__ float red[4][64];
    red[slot][lane] = acc;
    __syncthreads();
    if (slot == 0) {
        float a = red[0][lane] + red[1][lane] + red[2][lane] + red[3][lane];
        float cc = fmaxf((float)(s1 - s0), 1.0f);
        mols[g * 64 + lane] = a / cc;
    }
}

__global__ void k_mlp(const float* __restrict__ mols,
                      const float* __restrict__ fc1W, const float* __restrict__ fc1b,
                      const float* __restrict__ fcsW, const float* __restrict__ fcsb,
                      const float* __restrict__ outW, const float* __restrict__ outb,
                      float* __restrict__ y) {
    int g = blockIdx.x, t = threadIdx.x; // 128 threads
    __shared__ float m[64];
    __shared__ float h[128];
    __shared__ float rbuf[128];
    if (t < 64) m[t] = mols[g * 64 + t];
    __syncthreads();
    float a = fc1b[t];
#pragma unroll 4
    for (int k = 0; k < 64; k++) a += m[k] * fc1W[k * 128 + t];
    h[t] = softplus_ref(a);
    __syncthreads();
    for (int i = 0; i < 3; i++) {
        float b = fcsb[i * 128 + t];
#pragma unroll 4
        for (int k = 0; k < 128; k++) b += h[k] * fcsW[((size_t)i * 128 + k) * 128 + t];
        __syncthreads();
        h[t] = softplus_ref(b);
        __syncthreads();
    }
    rbuf[t] = h[t] * outW[t];
    __syncthreads();
    if (t < 64) {
        float s2 = rbuf[t] + rbuf[t + 64];
#pragma unroll
        for (int off = 32; off; off >>= 1) s2 += __shfl_xor(s2, off, 64);
        if (t == 0) y[g] = s2 + outb[0];
    }
}

extern "C" void kernel_launch(void* const* d_in, const int* in_sizes, int n_in,
                              void* d_out, int out_size, void* d_ws, size_t ws_size,
                              hipStream_t stream) {
    const int*   an    = (const int*)d_in[0];
    const int*   nbr   = (const int*)d_in[1];
    const float* dist  = (const float*)d_in[2];
    const int*   batch = (const int*)d_in[3];
    const float* emb   = (const float*)d_in[4];
    const float* nucW  = (const float*)d_in[5];
    const float* nucB  = (const float*)d_in[6];
    const float* convW = (const float*)d_in[7];
    const float* convB = (const float*)d_in[8];
    const float* bng   = (const float*)d_in[9];
    const float* bnb   = (const float*)d_in[10];
    const float* lng   = (const float*)d_in[11];
    const float* lnb   = (const float*)d_in[12];
    const float* fc1W  = (const float*)d_in[13];
    const float* fc1b  = (const float*)d_in[14];
    const float* fcsW  = (const float*)d_in[15];
    const float* fcsb  = (const float*)d_in[16];
    const float* outW  = (const float*)d_in[17];
    const float* outb  = (const float*)d_in[18];
    const int* srcI = nbr;
    const int* dstI = nbr + EE;

    char* base = (char*)d_ws;
    size_t off = 0;
    auto alloc = [&](size_t b) { size_t r = off; off += (b + 255) & ~(size_t)255; return r; };
    float*   gtab   = (float*)(base + alloc((size_t)TS * 100 * 4));
    __half2* Tall   = (__half2*)(base + alloc((size_t)6 * TS * 64 * 4));
    float*   x0     = (float*)(base + alloc((size_t)NN * 64 * 4));
    float*   x1     = (float*)(base + alloc((size_t)NN * 64 * 4));
    __half2* up     = (__half2*)(base + alloc((size_t)NN * 64 * 4));
    __half2* vp     = (__half2*)(base + alloc((size_t)NN * 64 * 4));
    float*   sums   = (float*)(base + alloc(256 * 4));
    float*   AB     = (float*)(base + alloc(256 * 4));
    int*     counts = (int*)(base + alloc((size_t)NN * 4));
    int*     cursor = (int*)(base + alloc((size_t)NN * 4));
    int*     rp     = (int*)(base + alloc((size_t)(NN + 1) * 4));
    int*     perm   = (int*)(base + alloc((size_t)EE * 4));
    float*   mols   = (float*)(base + alloc((size_t)GG * 64 * 4));
    int*     gp     = (int*)(base + alloc((size_t)(GG + 1) * 4));
    size_t zbytes = (size_t)EE * 64 * 4;   // 128 MB fp16 pairs
    __half2* zbuf = nullptr;
    if (off + zbytes <= ws_size) { zbuf = (__half2*)(base + alloc(zbytes)); }

    hipMemsetAsync(counts, 0, (size_t)NN * 4, stream);
    hipMemsetAsync(cursor, 0, (size_t)NN * 4, stream);
    hipMemsetAsync(sums, 0, 256 * 4, stream);

    k_gtab<<<(TS * 100 + 255) / 256, 256, 0, stream>>>(gtab);
    k_build_T<<<dim3(TS, 6), 64, 0, stream>>>(gtab, convW, convB, Tall);
    k_embed<<<(NN + 3) / 4, 256, 0, stream>>>(an, emb, nucW, nucB, x0);
    k_hist<<<(EE + 255) / 256, 256, 0, stream>>>(dstI, counts);
    k_scan<<<1, 1024, 0, stream>>>(counts, rp);
    k_scatter<<<(EE + 255) / 256, 256, 0, stream>>>(dstI, rp, cursor, perm);
    k_gp<<<1, 128, 0, stream>>>(batch, gp);

    float* xin = x0;
    float* xout = x1;
    for (int l = 0; l < 6; l++) {
        k_uv<<<(NN + 3) / 4, 256, 0, stream>>>(xin, convW, l, up, vp);
        const __half2* Tl = Tall + (size_t)l * TS * 64;
        k_zstats<<<NN, 256, 0, stream>>>(up, vp, Tl, srcI, dist, rp, perm, sums, zbuf);
        k_finalize<<<1, 128, 0, stream>>>(sums, bng, bnb, l, AB);
        if (zbuf)
            k_agg_z<<<NN, 256, 0, stream>>>(zbuf, rp, AB, lng, lnb, l, xin, xout);
        else
            k_agg_re<<<NN, 256, 0, stream>>>(up, vp, Tl, srcI, dist, rp, perm,
                                             AB, lng, lnb, l, xin, xout);
        float* tmp = xin; xin = xout; xout = tmp;
    }
    k_pool2<<<GG, 256, 0, stream>>>(xin, gp, mols);
    k_mlp<<<GG, 128, 0, stream>>>(mols, fc1W, fc1b, fcsW, fcsb, outW, outb, (float*)d_out);
}

// Round 3
// 1751.039 us; speedup vs baseline: 2.1558x; 2.1558x over previous
//
#include <hip/hip_runtime.h>
#include <hip/hip_fp16.h>
#include <cmath>

#define NN 20000
#define EE 500000
#define GG 64
#define TS 4096
#define EPS 1e-5f

__device__ __forceinline__ float softplus_ref(float x) {
    return fmaxf(x, 0.f) + log1pf(__expf(-fabsf(x)));
}
__device__ __forceinline__ float softplus_fast(float x) {
    return fmaxf(x, 0.f) + __logf(1.0f + __expf(-fabsf(x)));
}
__device__ __forceinline__ float sigmoid_fast(float x) {
    return __builtin_amdgcn_rcpf(1.0f + __expf(-x));
}

// gaussian table: g[s][k] = exp(coeff*(d_s - o_k)^2)
__global__ void k_gtab(float* __restrict__ g) {
    int i = blockIdx.x * 256 + threadIdx.x;
    if (i >= TS * 100) return;
    int s = i / 100, k = i - 100 * s;
    float d = s * (6.0f / 4095.0f);
    float o = k * (6.0f / 99.0f);
    float step = 6.0f / 99.0f;
    float coeff = -0.5f / (step * step);
    float df = d - o;
    g[i] = __expf(coeff * df * df);
}

// Paired layout: Tp[l][s][t] = half2(T[c=t], T[c=t+64])
__global__ void k_build_T(const float* __restrict__ g, const float* __restrict__ convW,
                          const float* __restrict__ convB, __half2* __restrict__ Tp) {
    int t = threadIdx.x;            // 64
    int s = blockIdx.x;             // TS
    int l = blockIdx.y;             // 6
    const float* gr = g + (size_t)s * 100;
    const float* w = convW + ((size_t)l * 228 + 128) * 128;
    float a0 = convB[l * 128 + t];
    float a1 = convB[l * 128 + t + 64];
#pragma unroll 4
    for (int k = 0; k < 100; k++) {
        float gv = gr[k];
        a0 += gv * w[k * 128 + t];
        a1 += gv * w[k * 128 + t + 64];
    }
    Tp[((size_t)l * TS + s) * 64 + t] = __floats2half2_rn(a0, a1);
}

__global__ void k_embed(const int* __restrict__ an, const float* __restrict__ emb,
                        const float* __restrict__ W, const float* __restrict__ b,
                        float* __restrict__ x) {
    int c = threadIdx.x & 63, nl = threadIdx.x >> 6;
    int n = blockIdx.x * 4 + nl;
    if (n >= NN) return;
    const float* e = emb + (size_t)an[n] * 92;
    float acc = b[c];
#pragma unroll 4
    for (int k = 0; k < 92; k++) acc += e[k] * W[k * 64 + c];
    x[(size_t)n * 64 + c] = acc;
}

__global__ void k_hist(const int* __restrict__ dst, int* __restrict__ counts) {
    int e = blockIdx.x * 256 + threadIdx.x;
    if (e < EE) atomicAdd(&counts[dst[e]], 1);
}

__global__ void k_scan(const int* __restrict__ counts, int* __restrict__ rp) {
    __shared__ int buf[1024];
    __shared__ int carry;
    int tid = threadIdx.x;
    if (tid == 0) { carry = 0; rp[0] = 0; }
    __syncthreads();
    for (int base = 0; base < NN; base += 1024) {
        int i = base + tid;
        int val = (i < NN) ? counts[i] : 0;
        buf[tid] = val;
        __syncthreads();
        for (int off = 1; off < 1024; off <<= 1) {
            int t = (tid >= off) ? buf[tid - off] : 0;
            __syncthreads();
            buf[tid] += t;
            __syncthreads();
        }
        if (i < NN) rp[i + 1] = carry + buf[tid];
        __syncthreads();
        if (tid == 0) carry += buf[1023];
        __syncthreads();
    }
}

__global__ void k_scatter(const int* __restrict__ dst, const int* __restrict__ rp,
                          int* __restrict__ cursor, int* __restrict__ perm) {
    int e = blockIdx.x * 256 + threadIdx.x;
    if (e < EE) {
        int d = dst[e];
        int p = atomicAdd(&cursor[d], 1);
        perm[rp[d] + p] = e;
    }
}

// pre-permuted edge data: srcP[idx] = src[perm[idx]], jfP = packed (j<<20)|f_q20
__global__ void k_edges(const int* __restrict__ perm, const int* __restrict__ src,
                        const float* __restrict__ dist,
                        int* __restrict__ srcP, unsigned* __restrict__ jfP) {
    int idx = blockIdx.x * 256 + threadIdx.x;
    if (idx >= EE) return;
    int e = perm[idx];
    srcP[idx] = src[e];
    float t = dist[e] * (4095.0f / 6.0f);
    int j = (int)t;
    if (j > TS - 2) j = TS - 2;
    float f = t - (float)j;
    f = fminf(fmaxf(f, 0.0f), 0.9999995f);
    unsigned fq = (unsigned)(f * 1048576.0f);
    if (fq > 1048575u) fq = 1048575u;
    jfP[idx] = ((unsigned)j << 20) | fq;
}

// u,v in paired layout: up[n][t] = half2(u_t, u_{t+64})
__global__ void k_uv(const float* __restrict__ x, const float* __restrict__ convW,
                     int l, __half2* __restrict__ up, __half2* __restrict__ vp) {
    int lane = threadIdx.x & 63;
    int n = blockIdx.x * 4 + (threadIdx.x >> 6);
    if (n >= NN) return;
    float xv = x[(size_t)n * 64 + lane];
    const float* W1 = convW + (size_t)l * 228 * 128;          // rows 0..63   (dst half)
    const float* W2 = W1 + (size_t)64 * 128;                  // rows 64..127 (src half)
    float a0 = 0.f, a1 = 0.f, b0 = 0.f, b1 = 0.f;
#pragma unroll 4
    for (int k = 0; k < 64; k++) {
        float xk = __shfl(xv, k, 64);
        const float* r1 = W1 + (size_t)k * 128;
        const float* r2 = W2 + (size_t)k * 128;
        a0 += xk * r1[lane]; a1 += xk * r1[lane + 64];
        b0 += xk * r2[lane]; b1 += xk * r2[lane + 64];
    }
    up[(size_t)n * 64 + lane] = __floats2half2_rn(a0, a1);
    vp[(size_t)n * 64 + lane] = __floats2half2_rn(b0, b1);
}

// pass A: BN stats, wave-per-node (node-strided), no LDS, recompute z
__global__ void __launch_bounds__(256) k_stats2(
    const __half2* __restrict__ up, const __half2* __restrict__ vp,
    const __half2* __restrict__ Tp,
    const int* __restrict__ srcP, const unsigned* __restrict__ jfP,
    const int* __restrict__ rp, float* __restrict__ sums) {
    int lane = threadIdx.x & 63;
    int wv = threadIdx.x >> 6;
    float sx = 0.f, sy = 0.f, qx = 0.f, qy = 0.f;
    for (int i = blockIdx.x * 4 + wv; i < NN; i += gridDim.x * 4) {
        float2 uu = __half22float2(up[(size_t)i * 64 + lane]);
        int rs = rp[i], re = rp[i + 1];
        if (rs >= re) continue;
        int sN = srcP[rs]; unsigned jN = jfP[rs];
        for (int idx = rs; idx < re; ++idx) {
            int si = sN; unsigned jf = jN;
            if (idx + 1 < re) { sN = srcP[idx + 1]; jN = jfP[idx + 1]; }
            int j = jf >> 20;
            float f = (float)(jf & 0xFFFFFu) * (1.0f / 1048576.0f);
            float2 vv = __half22float2(vp[(size_t)si * 64 + lane]);
            float2 t0 = __half22float2(Tp[(size_t)j * 64 + lane]);
            float2 t1 = __half22float2(Tp[(size_t)(j + 1) * 64 + lane]);
            float z0 = uu.x + vv.x + t0.x + (t1.x - t0.x) * f;
            float z1 = uu.y + vv.y + t0.y + (t1.y - t0.y) * f;
            sx += z0; qx += z0 * z0;
            sy += z1; qy += z1 * z1;
        }
    }
    atomicAdd(&sums[lane], sx);
    atomicAdd(&sums[lane + 64], sy);
    atomicAdd(&sums[128 + lane], qx);
    atomicAdd(&sums[192 + lane], qy);
}

__global__ void k_finalize(float* __restrict__ sums, const float* __restrict__ bn_g,
                           const float* __restrict__ bn_b, int l, float* __restrict__ AB) {
    int c = threadIdx.x; // 128
    float mu = sums[c] * (1.0f / EE);
    float ms = sums[128 + c] * (1.0f / EE);
    float var = ms - mu * mu;
    float rstd = rsqrtf(var + EPS);
    float A = rstd * bn_g[l * 128 + c];
    float B = bn_b[l * 128 + c] - mu * A;
    AB[c] = A; AB[128 + c] = B;
    sums[c] = 0.f; sums[128 + c] = 0.f;
}

// pass B: recompute z, BN, sigmoid*softplus, aggregate; wave-per-node, no LDS;
// LN + residual + softplus epilogue in shuffles
__global__ void __launch_bounds__(256) k_agg(
    const __half2* __restrict__ up, const __half2* __restrict__ vp,
    const __half2* __restrict__ Tp,
    const int* __restrict__ srcP, const unsigned* __restrict__ jfP,
    const int* __restrict__ rp,
    const float* __restrict__ AB, const float* __restrict__ lng, const float* __restrict__ lnb,
    int l, const float* __restrict__ xin, float* __restrict__ xout) {
    int lane = threadIdx.x & 63;
    int i = blockIdx.x * 4 + (threadIdx.x >> 6);
    if (i >= NN) return;
    float A1 = AB[lane], A2 = AB[lane + 64];
    float B1 = AB[128 + lane], B2 = AB[192 + lane];
    float2 uu = __half22float2(up[(size_t)i * 64 + lane]);
    float acc = 0.f;
    int rs = rp[i], re = rp[i + 1];
    if (rs < re) {
        int sN = srcP[rs]; unsigned jN = jfP[rs];
        for (int idx = rs; idx < re; ++idx) {
            int si = sN; unsigned jf = jN;
            if (idx + 1 < re) { sN = srcP[idx + 1]; jN = jfP[idx + 1]; }
            int j = jf >> 20;
            float f = (float)(jf & 0xFFFFFu) * (1.0f / 1048576.0f);
            float2 vv = __half22float2(vp[(size_t)si * 64 + lane]);
            float2 t0 = __half22float2(Tp[(size_t)j * 64 + lane]);
            float2 t1 = __half22float2(Tp[(size_t)(j + 1) * 64 + lane]);
            float z1 = (uu.x + vv.x + t0.x + (t1.x - t0.x) * f) * A1 + B1;
            float z2 = (uu.y + vv.y + t0.y + (t1.y - t0.y) * f) * A2 + B2;
            acc += sigmoid_fast(z1) * softplus_fast(z2);
        }
    }
    float s = acc;
#pragma unroll
    for (int off = 32; off; off >>= 1) s += __shfl_xor(s, off, 64);
    float mean = s * (1.0f / 64.0f);
    float e0 = acc - mean;
    float vv2 = e0 * e0;
#pragma unroll
    for (int off = 32; off; off >>= 1) vv2 += __shfl_xor(vv2, off, 64);
    float var = vv2 * (1.0f / 64.0f);
    float h = e0 * rsqrtf(var + EPS) * lng[l * 64 + lane] + lnb[l * 64 + lane];
    xout[(size_t)i * 64 + lane] = softplus_ref(h + xin[(size_t)i * 64 + lane]);
}

// batch sorted -> graph row pointers by binary search
__global__ void k_gp(const int* __restrict__ batch, int* __restrict__ gp) {
    int g = threadIdx.x;
    if (g > GG) return;
    int lo = 0, hi = NN;
    while (lo < hi) {
        int mid = (lo + hi) >> 1;
        if (batch[mid] < g) lo = mid + 1; else hi = mid;
    }
    gp[g] = lo;
}

// atomic-free segmented mean-pool
__global__ void k_pool2(const float* __restrict__ x, const int* __restrict__ gp,
                        float* __restrict__ mols) {
    int g = blockIdx.x;
    int lane = threadIdx.x & 63, slot = threadIdx.x >> 6;
    int s0 = gp[g], s1 = gp[g + 1];
    float acc = 0.f;
    for (int n = s0 + slot; n < s1; n += 4) acc += x[(size_t)n * 64 + lane];
    __shared__ float red[4][64];
    red[slot][lane] = acc;
    __syncthreads();
    if (slot == 0) {
        float a = red[0][lane] + red[1][lane] + red[2][lane] + red[3][lane];
        float cc = fmaxf((float)(s1 - s0), 1.0f);
        mols[g * 64 + lane] = a / cc;
    }
}

__global__ void k_mlp(const float* __restrict__ mols,
                      const float* __restrict__ fc1W, const float* __restrict__ fc1b,
                      const float* __restrict__ fcsW, const float* __restrict__ fcsb,
                      const float* __restrict__ outW, const float* __restrict__ outb,
                      float* __restrict__ y) {
    int g = blockIdx.x, t = threadIdx.x; // 128 threads
    __shared__ float m[64];
    __shared__ float h[128];
    __shared__ float rbuf[128];
    if (t < 64) m[t] = mols[g * 64 + t];
    __syncthreads();
    float a = fc1b[t];
#pragma unroll 4
    for (int k = 0; k < 64; k++) a += m[k] * fc1W[k * 128 + t];
    h[t] = softplus_ref(a);
    __syncthreads();
    for (int i = 0; i < 3; i++) {
        float b = fcsb[i * 128 + t];
#pragma unroll 4
        for (int k = 0; k < 128; k++) b += h[k] * fcsW[((size_t)i * 128 + k) * 128 + t];
        __syncthreads();
        h[t] = softplus_ref(b);
        __syncthreads();
    }
    rbuf[t] = h[t] * outW[t];
    __syncthreads();
    if (t < 64) {
        float s2 = rbuf[t] + rbuf[t + 64];
#pragma unroll
        for (int off = 32; off; off >>= 1) s2 += __shfl_xor(s2, off, 64);
        if (t == 0) y[g] = s2 + outb[0];
    }
}

extern "C" void kernel_launch(void* const* d_in, const int* in_sizes, int n_in,
                              void* d_out, int out_size, void* d_ws, size_t ws_size,
                              hipStream_t stream) {
    const int*   an    = (const int*)d_in[0];
    const int*   nbr   = (const int*)d_in[1];
    const float* dist  = (const float*)d_in[2];
    const int*   batch = (const int*)d_in[3];
    const float* emb   = (const float*)d_in[4];
    const float* nucW  = (const float*)d_in[5];
    const float* nucB  = (const float*)d_in[6];
    const float* convW = (const float*)d_in[7];
    const float* convB = (const float*)d_in[8];
    const float* bng   = (const float*)d_in[9];
    const float* bnb   = (const float*)d_in[10];
    const float* lng   = (const float*)d_in[11];
    const float* lnb   = (const float*)d_in[12];
    const float* fc1W  = (const float*)d_in[13];
    const float* fc1b  = (const float*)d_in[14];
    const float* fcsW  = (const float*)d_in[15];
    const float* fcsb  = (const float*)d_in[16];
    const float* outW  = (const float*)d_in[17];
    const float* outb  = (const float*)d_in[18];
    const int* srcI = nbr;
    const int* dstI = nbr + EE;

    char* base = (char*)d_ws;
    size_t off = 0;
    auto alloc = [&](size_t b) { size_t r = off; off += (b + 255) & ~(size_t)255; return r; };
    float*    gtab   = (float*)(base + alloc((size_t)TS * 100 * 4));
    __half2*  Tall   = (__half2*)(base + alloc((size_t)6 * TS * 64 * 4));
    float*    x0     = (float*)(base + alloc((size_t)NN * 64 * 4));
    float*    x1     = (float*)(base + alloc((size_t)NN * 64 * 4));
    __half2*  up     = (__half2*)(base + alloc((size_t)NN * 64 * 4));
    __half2*  vp     = (__half2*)(base + alloc((size_t)NN * 64 * 4));
    float*    sums   = (float*)(base + alloc(256 * 4));
    float*    AB     = (float*)(base + alloc(256 * 4));
    int*      counts = (int*)(base + alloc((size_t)NN * 4));
    int*      cursor = (int*)(base + alloc((size_t)NN * 4));
    int*      rp     = (int*)(base + alloc((size_t)(NN + 1) * 4));
    int*      perm   = (int*)(base + alloc((size_t)EE * 4));
    int*      srcP   = (int*)(base + alloc((size_t)EE * 4));
    unsigned* jfP    = (unsigned*)(base + alloc((size_t)EE * 4));
    float*    mols   = (float*)(base + alloc((size_t)GG * 64 * 4));
    int*      gp     = (int*)(base + alloc((size_t)(GG + 1) * 4));

    hipMemsetAsync(counts, 0, (size_t)NN * 4, stream);
    hipMemsetAsync(cursor, 0, (size_t)NN * 4, stream);
    hipMemsetAsync(sums, 0, 256 * 4, stream);

    k_gtab<<<(TS * 100 + 255) / 256, 256, 0, stream>>>(gtab);
    k_build_T<<<dim3(TS, 6), 64, 0, stream>>>(gtab, convW, convB, Tall);
    k_embed<<<(NN + 3) / 4, 256, 0, stream>>>(an, emb, nucW, nucB, x0);
    k_hist<<<(EE + 255) / 256, 256, 0, stream>>>(dstI, counts);
    k_scan<<<1, 1024, 0, stream>>>(counts, rp);
    k_scatter<<<(EE + 255) / 256, 256, 0, stream>>>(dstI, rp, cursor, perm);
    k_edges<<<(EE + 255) / 256, 256, 0, stream>>>(perm, srcI, dist, srcP, jfP);
    k_gp<<<1, 128, 0, stream>>>(batch, gp);

    float* xin = x0;
    float* xout = x1;
    for (int l = 0; l < 6; l++) {
        k_uv<<<(NN + 3) / 4, 256, 0, stream>>>(xin, convW, l, up, vp);
        const __half2* Tl = Tall + (size_t)l * TS * 64;
        k_stats2<<<1024, 256, 0, stream>>>(up, vp, Tl, srcP, jfP, rp, sums);
        k_finalize<<<1, 128, 0, stream>>>(sums, bng, bnb, l, AB);
        k_agg<<<(NN + 3) / 4, 256, 0, stream>>>(up, vp, Tl, srcP, jfP, rp,
                                                AB, lng, lnb, l, xin, xout);
        float* tmp = xin; xin = xout; xout = tmp;
    }
    k_pool2<<<GG, 256, 0, stream>>>(xin, gp, mols);
    k_mlp<<<GG, 128, 0, stream>>>(mols, fc1W, fc1b, fcsW, fcsb, outW, outb, (float*)d_out);
}

// Round 4
// 1343.010 us; speedup vs baseline: 2.8107x; 1.3038x over previous
//
#include <hip/hip_runtime.h>
#include <hip/hip_fp16.h>
#include <cmath>

#define NN 20000
#define EE 500000
#define GG 64
#define TS 4096
#define EPS 1e-5f

__device__ __forceinline__ float softplus_ref(float x) {
    return fmaxf(x, 0.f) + log1pf(__expf(-fabsf(x)));
}
__device__ __forceinline__ float softplus_fast(float x) {
    return fmaxf(x, 0.f) + __logf(1.0f + __expf(-fabsf(x)));
}
__device__ __forceinline__ float sigmoid_fast(float x) {
    return __builtin_amdgcn_rcpf(1.0f + __expf(-x));
}

// gaussian table: g[s][k] = exp(coeff*(d_s - o_k)^2)
__global__ void k_gtab(float* __restrict__ g) {
    int i = blockIdx.x * 256 + threadIdx.x;
    if (i >= TS * 100) return;
    int s = i / 100, k = i - 100 * s;
    float d = s * (6.0f / 4095.0f);
    float o = k * (6.0f / 99.0f);
    float step = 6.0f / 99.0f;
    float coeff = -0.5f / (step * step);
    float df = d - o;
    g[i] = __expf(coeff * df * df);
}

// Paired channel layout: Tp[l][s][t] = half2(T[c=t], T[c=t+64])
__global__ void k_build_T(const float* __restrict__ g, const float* __restrict__ convW,
                          const float* __restrict__ convB, __half2* __restrict__ Tp) {
    int t = threadIdx.x;            // 64
    int s = blockIdx.x;             // TS
    int l = blockIdx.y;             // 6
    const float* gr = g + (size_t)s * 100;
    const float* w = convW + ((size_t)l * 228 + 128) * 128;
    float a0 = convB[l * 128 + t];
    float a1 = convB[l * 128 + t + 64];
#pragma unroll 4
    for (int k = 0; k < 100; k++) {
        float gv = gr[k];
        a0 += gv * w[k * 128 + t];
        a1 += gv * w[k * 128 + t + 64];
    }
    Tp[((size_t)l * TS + s) * 64 + t] = __floats2half2_rn(a0, a1);
}

// Row-pair layout: Tq[l][j][t] = uint2( Tp[l][j][t], Tp[l][j+1][t] )  (one dwordx2 gather)
__global__ void k_build_Tq(const __half2* __restrict__ Tp, uint2* __restrict__ Tq) {
    int t = threadIdx.x;            // 64
    int j = blockIdx.x;             // TS
    int l = blockIdx.y;             // 6
    int j1 = min(j + 1, TS - 1);
    unsigned lo = *(const unsigned*)&Tp[((size_t)l * TS + j) * 64 + t];
    unsigned hi = *(const unsigned*)&Tp[((size_t)l * TS + j1) * 64 + t];
    Tq[((size_t)l * TS + j) * 64 + t] = make_uint2(lo, hi);
}

__global__ void k_embed(const int* __restrict__ an, const float* __restrict__ emb,
                        const float* __restrict__ W, const float* __restrict__ b,
                        float* __restrict__ x) {
    int c = threadIdx.x & 63, nl = threadIdx.x >> 6;
    int n = blockIdx.x * 4 + nl;
    if (n >= NN) return;
    const float* e = emb + (size_t)an[n] * 92;
    float acc = b[c];
#pragma unroll 4
    for (int k = 0; k < 92; k++) acc += e[k] * W[k * 64 + c];
    x[(size_t)n * 64 + c] = acc;
}

__global__ void k_hist(const int* __restrict__ dst, int* __restrict__ counts) {
    int e = blockIdx.x * 256 + threadIdx.x;
    if (e < EE) atomicAdd(&counts[dst[e]], 1);
}

__global__ void k_scan(const int* __restrict__ counts, int* __restrict__ rp) {
    __shared__ int buf[1024];
    __shared__ int carry;
    int tid = threadIdx.x;
    if (tid == 0) { carry = 0; rp[0] = 0; }
    __syncthreads();
    for (int base = 0; base < NN; base += 1024) {
        int i = base + tid;
        int val = (i < NN) ? counts[i] : 0;
        buf[tid] = val;
        __syncthreads();
        for (int off = 1; off < 1024; off <<= 1) {
            int t = (tid >= off) ? buf[tid - off] : 0;
            __syncthreads();
            buf[tid] += t;
            __syncthreads();
        }
        if (i < NN) rp[i + 1] = carry + buf[tid];
        __syncthreads();
        if (tid == 0) carry += buf[1023];
        __syncthreads();
    }
}

__global__ void k_scatter(const int* __restrict__ dst, const int* __restrict__ rp,
                          int* __restrict__ cursor, int* __restrict__ perm) {
    int e = blockIdx.x * 256 + threadIdx.x;
    if (e < EE) {
        int d = dst[e];
        int p = atomicAdd(&cursor[d], 1);
        perm[rp[d] + p] = e;
    }
}

// packed edge record in perm order: ej[idx] = { src, (j<<20)|f_q20 }
__global__ void k_edges(const int* __restrict__ perm, const int* __restrict__ src,
                        const float* __restrict__ dist, int2* __restrict__ ej) {
    int idx = blockIdx.x * 256 + threadIdx.x;
    if (idx >= EE) return;
    int e = perm[idx];
    float t = dist[e] * (4095.0f / 6.0f);
    int j = (int)t;
    if (j > TS - 2) j = TS - 2;
    float f = t - (float)j;
    f = fminf(fmaxf(f, 0.0f), 0.9999995f);
    unsigned fq = (unsigned)(f * 1048576.0f);
    if (fq > 1048575u) fq = 1048575u;
    ej[idx] = make_int2(src[e], (int)(((unsigned)j << 20) | fq));
}

// u,v in paired layout: up[n][t] = half2(u_t, u_{t+64})
__global__ void k_uv(const float* __restrict__ x, const float* __restrict__ convW,
                     int l, __half2* __restrict__ up, __half2* __restrict__ vp) {
    int lane = threadIdx.x & 63;
    int n = blockIdx.x * 4 + (threadIdx.x >> 6);
    if (n >= NN) return;
    float xv = x[(size_t)n * 64 + lane];
    const float* W1 = convW + (size_t)l * 228 * 128;          // rows 0..63   (dst half)
    const float* W2 = W1 + (size_t)64 * 128;                  // rows 64..127 (src half)
    float a0 = 0.f, a1 = 0.f, b0 = 0.f, b1 = 0.f;
#pragma unroll 4
    for (int k = 0; k < 64; k++) {
        float xk = __shfl(xv, k, 64);
        const float* r1 = W1 + (size_t)k * 128;
        const float* r2 = W2 + (size_t)k * 128;
        a0 += xk * r1[lane]; a1 += xk * r1[lane + 64];
        b0 += xk * r2[lane]; b1 += xk * r2[lane + 64];
    }
    up[(size_t)n * 64 + lane] = __floats2half2_rn(a0, a1);
    vp[(size_t)n * 64 + lane] = __floats2half2_rn(b0, b1);
}

__device__ __forceinline__ void edge_z(const __half2* __restrict__ vp,
                                       const uint2* __restrict__ Tq,
                                       int2 e, int lane, float2 uu,
                                       float& z0, float& z1) {
    int si = e.x;
    unsigned jf = (unsigned)e.y;
    int j = jf >> 20;
    float f = (float)(jf & 0xFFFFFu) * (1.0f / 1048576.0f);
    float2 vv = __half22float2(vp[(size_t)si * 64 + lane]);
    uint2 tq = Tq[(size_t)j * 64 + lane];
    float2 t0 = __half22float2(*(const __half2*)&tq.x);
    float2 t1 = __half22float2(*(const __half2*)&tq.y);
    z0 = uu.x + vv.x + t0.x + (t1.x - t0.x) * f;
    z1 = uu.y + vv.y + t0.y + (t1.y - t0.y) * f;
}

// pass A: BN stats; node-strided waves, 4-way edge ILP, LDS block-reduce
__global__ void __launch_bounds__(256) k_stats(
    const __half2* __restrict__ up, const __half2* __restrict__ vp,
    const uint2* __restrict__ Tq, const int2* __restrict__ ej,
    const int* __restrict__ rp, float* __restrict__ sums) {
    int lane = threadIdx.x & 63;
    int wv = threadIdx.x >> 6;
    float sx = 0.f, sy = 0.f, qx = 0.f, qy = 0.f;
    for (int i = blockIdx.x * 4 + wv; i < NN; i += gridDim.x * 4) {
        float2 uu = __half22float2(up[(size_t)i * 64 + lane]);
        int rs = rp[i], re = rp[i + 1];
        int idx = rs;
        for (; idx + 4 <= re; idx += 4) {
            int2 e0 = ej[idx], e1 = ej[idx + 1], e2 = ej[idx + 2], e3 = ej[idx + 3];
            float a0, a1, b0, b1, c0, c1, d0, d1;
            edge_z(vp, Tq, e0, lane, uu, a0, a1);
            edge_z(vp, Tq, e1, lane, uu, b0, b1);
            edge_z(vp, Tq, e2, lane, uu, c0, c1);
            edge_z(vp, Tq, e3, lane, uu, d0, d1);
            sx += a0 + b0 + c0 + d0;
            sy += a1 + b1 + c1 + d1;
            qx += a0 * a0 + b0 * b0 + c0 * c0 + d0 * d0;
            qy += a1 * a1 + b1 * b1 + c1 * c1 + d1 * d1;
        }
        for (; idx < re; ++idx) {
            float z0, z1;
            edge_z(vp, Tq, ej[idx], lane, uu, z0, z1);
            sx += z0; qx += z0 * z0;
            sy += z1; qy += z1 * z1;
        }
    }
    __shared__ float red[4][64][4];
    red[wv][lane][0] = sx; red[wv][lane][1] = sy;
    red[wv][lane][2] = qx; red[wv][lane][3] = qy;
    __syncthreads();
    if (wv == 0) {
        for (int r = 1; r < 4; r++) {
            sx += red[r][lane][0]; sy += red[r][lane][1];
            qx += red[r][lane][2]; qy += red[r][lane][3];
        }
        atomicAdd(&sums[lane], sx);
        atomicAdd(&sums[lane + 64], sy);
        atomicAdd(&sums[128 + lane], qx);
        atomicAdd(&sums[192 + lane], qy);
    }
}

__global__ void k_finalize(float* __restrict__ sums, const float* __restrict__ bn_g,
                           const float* __restrict__ bn_b, int l, float* __restrict__ AB) {
    int c = threadIdx.x; // 128
    float mu = sums[c] * (1.0f / EE);
    float ms = sums[128 + c] * (1.0f / EE);
    float var = ms - mu * mu;
    float rstd = rsqrtf(var + EPS);
    float A = rstd * bn_g[l * 128 + c];
    float B = bn_b[l * 128 + c] - mu * A;
    AB[c] = A; AB[128 + c] = B;
    sums[c] = 0.f; sums[128 + c] = 0.f;
}

// pass B: recompute z, BN, sigmoid*softplus, aggregate; wave-per-node, 4-way ILP;
// LN + residual + softplus epilogue in shuffles
__global__ void __launch_bounds__(256) k_agg(
    const __half2* __restrict__ up, const __half2* __restrict__ vp,
    const uint2* __restrict__ Tq, const int2* __restrict__ ej,
    const int* __restrict__ rp,
    const float* __restrict__ AB, const float* __restrict__ lng, const float* __restrict__ lnb,
    int l, const float* __restrict__ xin, float* __restrict__ xout) {
    int lane = threadIdx.x & 63;
    int i = blockIdx.x * 4 + (threadIdx.x >> 6);
    if (i >= NN) return;
    float A1 = AB[lane], A2 = AB[lane + 64];
    float B1 = AB[128 + lane], B2 = AB[192 + lane];
    float2 uu = __half22float2(up[(size_t)i * 64 + lane]);
    float xr = xin[(size_t)i * 64 + lane];
    float acc = 0.f;
    int rs = rp[i], re = rp[i + 1];
    int idx = rs;
    for (; idx + 4 <= re; idx += 4) {
        int2 e0 = ej[idx], e1 = ej[idx + 1], e2 = ej[idx + 2], e3 = ej[idx + 3];
        float a0, a1, b0, b1, c0, c1, d0, d1;
        edge_z(vp, Tq, e0, lane, uu, a0, a1);
        edge_z(vp, Tq, e1, lane, uu, b0, b1);
        edge_z(vp, Tq, e2, lane, uu, c0, c1);
        edge_z(vp, Tq, e3, lane, uu, d0, d1);
        acc += sigmoid_fast(a0 * A1 + B1) * softplus_fast(a1 * A2 + B2);
        acc += sigmoid_fast(b0 * A1 + B1) * softplus_fast(b1 * A2 + B2);
        acc += sigmoid_fast(c0 * A1 + B1) * softplus_fast(c1 * A2 + B2);
        acc += sigmoid_fast(d0 * A1 + B1) * softplus_fast(d1 * A2 + B2);
    }
    for (; idx < re; ++idx) {
        float z0, z1;
        edge_z(vp, Tq, ej[idx], lane, uu, z0, z1);
        acc += sigmoid_fast(z0 * A1 + B1) * softplus_fast(z1 * A2 + B2);
    }
    float s = acc;
#pragma unroll
    for (int off = 32; off; off >>= 1) s += __shfl_xor(s, off, 64);
    float mean = s * (1.0f / 64.0f);
    float e0v = acc - mean;
    float vv2 = e0v * e0v;
#pragma unroll
    for (int off = 32; off; off >>= 1) vv2 += __shfl_xor(vv2, off, 64);
    float var = vv2 * (1.0f / 64.0f);
    float h = e0v * rsqrtf(var + EPS) * lng[l * 64 + lane] + lnb[l * 64 + lane];
    xout[(size_t)i * 64 + lane] = softplus_ref(h + xr);
}

// batch sorted -> graph row pointers by binary search
__global__ void k_gp(const int* __restrict__ batch, int* __restrict__ gp) {
    int g = threadIdx.x;
    if (g > GG) return;
    int lo = 0, hi = NN;
    while (lo < hi) {
        int mid = (lo + hi) >> 1;
        if (batch[mid] < g) lo = mid + 1; else hi = mid;
    }
    gp[g] = lo;
}

// atomic-free segmented mean-pool
__global__ void k_pool2(const float* __restrict__ x, const int* __restrict__ gp,
                        float* __restrict__ mols) {
    int g = blockIdx.x;
    int lane = threadIdx.x & 63, slot = threadIdx.x >> 6;
    int s0 = gp[g], s1 = gp[g + 1];
    float acc = 0.f;
    for (int n = s0 + slot; n < s1; n += 4) acc += x[(size_t)n * 64 + lane];
    __shared__ float red[4][64];
    red[slot][lane] = acc;
    __syncthreads();
    if (slot == 0) {
        float a = red[0][lane] + red[1][lane] + red[2][lane] + red[3][lane];
        float cc = fmaxf((float)(s1 - s0), 1.0f);
        mols[g * 64 + lane] = a / cc;
    }
}

__global__ void k_mlp(const float* __restrict__ mols,
                      const float* __restrict__ fc1W, const float* __restrict__ fc1b,
                      const float* __restrict__ fcsW, const float* __restrict__ fcsb,
                      const float* __restrict__ outW, const float* __restrict__ outb,
                      float* __restrict__ y) {
    int g = blockIdx.x, t = threadIdx.x; // 128 threads
    __shared__ float m[64];
    __shared__ float h[128];
    __shared__ float rbuf[128];
    if (t < 64) m[t] = mols[g * 64 + t];
    __syncthreads();
    float a = fc1b[t];
#pragma unroll 4
    for (int k = 0; k < 64; k++) a += m[k] * fc1W[k * 128 + t];
    h[t] = softplus_ref(a);
    __syncthreads();
    for (int i = 0; i < 3; i++) {
        float b = fcsb[i * 128 + t];
#pragma unroll 4
        for (int k = 0; k < 128; k++) b += h[k] * fcsW[((size_t)i * 128 + k) * 128 + t];
        __syncthreads();
        h[t] = softplus_ref(b);
        __syncthreads();
    }
    rbuf[t] = h[t] * outW[t];
    __syncthreads();
    if (t < 64) {
        float s2 = rbuf[t] + rbuf[t + 64];
#pragma unroll
        for (int off = 32; off; off >>= 1) s2 += __shfl_xor(s2, off, 64);
        if (t == 0) y[g] = s2 + outb[0];
    }
}

extern "C" void kernel_launch(void* const* d_in, const int* in_sizes, int n_in,
                              void* d_out, int out_size, void* d_ws, size_t ws_size,
                              hipStream_t stream) {
    const int*   an    = (const int*)d_in[0];
    const int*   nbr   = (const int*)d_in[1];
    const float* dist  = (const float*)d_in[2];
    const int*   batch = (const int*)d_in[3];
    const float* emb   = (const float*)d_in[4];
    const float* nucW  = (const float*)d_in[5];
    const float* nucB  = (const float*)d_in[6];
    const float* convW = (const float*)d_in[7];
    const float* convB = (const float*)d_in[8];
    const float* bng   = (const float*)d_in[9];
    const float* bnb   = (const float*)d_in[10];
    const float* lng   = (const float*)d_in[11];
    const float* lnb   = (const float*)d_in[12];
    const float* fc1W  = (const float*)d_in[13];
    const float* fc1b  = (const float*)d_in[14];
    const float* fcsW  = (const float*)d_in[15];
    const float* fcsb  = (const float*)d_in[16];
    const float* outW  = (const float*)d_in[17];
    const float* outb  = (const float*)d_in[18];
    const int* srcI = nbr;
    const int* dstI = nbr + EE;

    char* base = (char*)d_ws;
    size_t off = 0;
    auto alloc = [&](size_t b) { size_t r = off; off += (b + 255) & ~(size_t)255; return r; };
    float*    gtab   = (float*)(base + alloc((size_t)TS * 100 * 4));
    __half2*  Tall   = (__half2*)(base + alloc((size_t)6 * TS * 64 * 4));
    uint2*    Tq     = (uint2*)(base + alloc((size_t)6 * TS * 64 * 8));
    float*    x0     = (float*)(base + alloc((size_t)NN * 64 * 4));
    float*    x1     = (float*)(base + alloc((size_t)NN * 64 * 4));
    __half2*  up     = (__half2*)(base + alloc((size_t)NN * 64 * 4));
    __half2*  vp     = (__half2*)(base + alloc((size_t)NN * 64 * 4));
    float*    sums   = (float*)(base + alloc(256 * 4));
    float*    AB     = (float*)(base + alloc(256 * 4));
    int*      counts = (int*)(base + alloc((size_t)NN * 4));
    int*      cursor = (int*)(base + alloc((size_t)NN * 4));
    int*      rp     = (int*)(base + alloc((size_t)(NN + 1) * 4));
    int*      perm   = (int*)(base + alloc((size_t)EE * 4));
    int2*     ej     = (int2*)(base + alloc((size_t)EE * 8));
    float*    mols   = (float*)(base + alloc((size_t)GG * 64 * 4));
    int*      gp     = (int*)(base + alloc((size_t)(GG + 1) * 4));

    hipMemsetAsync(counts, 0, (size_t)NN * 4, stream);
    hipMemsetAsync(cursor, 0, (size_t)NN * 4, stream);
    hipMemsetAsync(sums, 0, 256 * 4, stream);

    k_gtab<<<(TS * 100 + 255) / 256, 256, 0, stream>>>(gtab);
    k_build_T<<<dim3(TS, 6), 64, 0, stream>>>(gtab, convW, convB, Tall);
    k_build_Tq<<<dim3(TS, 6), 64, 0, stream>>>(Tall, Tq);
    k_embed<<<(NN + 3) / 4, 256, 0, stream>>>(an, emb, nucW, nucB, x0);
    k_hist<<<(EE + 255) / 256, 256, 0, stream>>>(dstI, counts);
    k_scan<<<1, 1024, 0, stream>>>(counts, rp);
    k_scatter<<<(EE + 255) / 256, 256, 0, stream>>>(dstI, rp, cursor, perm);
    k_edges<<<(EE + 255) / 256, 256, 0, stream>>>(perm, srcI, dist, ej);
    k_gp<<<1, 128, 0, stream>>>(batch, gp);

    float* xin = x0;
    float* xout = x1;
    for (int l = 0; l < 6; l++) {
        k_uv<<<(NN + 3) / 4, 256, 0, stream>>>(xin, convW, l, up, vp);
        const uint2* Tql = Tq + (size_t)l * TS * 64;
        k_stats<<<2048, 256, 0, stream>>>(up, vp, Tql, ej, rp, sums);
        k_finalize<<<1, 128, 0, stream>>>(sums, bng, bnb, l, AB);
        k_agg<<<(NN + 3) / 4, 256, 0, stream>>>(up, vp, Tql, ej, rp,
                                                AB, lng, lnb, l, xin, xout);
        float* tmp = xin; xin = xout; xout = tmp;
    }
    k_pool2<<<GG, 256, 0, stream>>>(xin, gp, mols);
    k_mlp<<<GG, 128, 0, stream>>>(mols, fc1W, fc1b, fcsW, fcsb, outW, outb, (float*)d_out);
}

// Round 5
// 1153.282 us; speedup vs baseline: 3.2731x; 1.1645x over previous
//
#include <hip/hip_runtime.h>
#include <hip/hip_fp16.h>
#include <cmath>

#define NN 20000
#define EE 500000
#define GG 64
#define TS 4096
#define EPS 1e-5f

__device__ __forceinline__ float softplus_ref(float x) {
    return fmaxf(x, 0.f) + log1pf(__expf(-fabsf(x)));
}
__device__ __forceinline__ float softplus_fast(float x) {
    return fmaxf(x, 0.f) + __logf(1.0f + __expf(-fabsf(x)));
}
__device__ __forceinline__ float sigmoid_fast(float x) {
    return __builtin_amdgcn_rcpf(1.0f + __expf(-x));
}

// gaussian table: g[s][k] = exp(coeff*(d_s - o_k)^2)
__global__ void k_gtab(float* __restrict__ g) {
    int i = blockIdx.x * 256 + threadIdx.x;
    if (i >= TS * 100) return;
    int s = i / 100, k = i - 100 * s;
    float d = s * (6.0f / 4095.0f);
    float o = k * (6.0f / 99.0f);
    float step = 6.0f / 99.0f;
    float coeff = -0.5f / (step * step);
    float df = d - o;
    g[i] = __expf(coeff * df * df);
}

// Paired channel layout: Tp[l][s][t] = half2(T[c=t], T[c=t+64])
__global__ void k_build_T(const float* __restrict__ g, const float* __restrict__ convW,
                          const float* __restrict__ convB, __half2* __restrict__ Tp) {
    int t = threadIdx.x;            // 64
    int s = blockIdx.x;             // TS
    int l = blockIdx.y;             // 6
    const float* gr = g + (size_t)s * 100;
    const float* w = convW + ((size_t)l * 228 + 128) * 128;
    float a0 = convB[l * 128 + t];
    float a1 = convB[l * 128 + t + 64];
#pragma unroll 4
    for (int k = 0; k < 100; k++) {
        float gv = gr[k];
        a0 += gv * w[k * 128 + t];
        a1 += gv * w[k * 128 + t + 64];
    }
    Tp[((size_t)l * TS + s) * 64 + t] = __floats2half2_rn(a0, a1);
}

// Row-pair layout: Tq[l][j][t] = uint2( Tp[l][j][t], Tp[l][j+1][t] )
__global__ void k_build_Tq(const __half2* __restrict__ Tp, uint2* __restrict__ Tq) {
    int t = threadIdx.x;            // 64
    int j = blockIdx.x;             // TS
    int l = blockIdx.y;             // 6
    int j1 = min(j + 1, TS - 1);
    unsigned lo = *(const unsigned*)&Tp[((size_t)l * TS + j) * 64 + t];
    unsigned hi = *(const unsigned*)&Tp[((size_t)l * TS + j1) * 64 + t];
    Tq[((size_t)l * TS + j) * 64 + t] = make_uint2(lo, hi);
}

// Wp[l][k][lane] = (W1[k,lane], W1[k,lane+64], W2[k,lane], W2[k,lane+64])
__global__ void k_prepW(const float* __restrict__ convW, float4* __restrict__ Wp) {
    int lane = threadIdx.x;  // 64
    int k = blockIdx.x;      // 64
    int l = blockIdx.y;      // 6
    const float* W1 = convW + ((size_t)l * 228 + k) * 128;
    const float* W2 = convW + ((size_t)l * 228 + 64 + k) * 128;
    Wp[((size_t)l * 64 + k) * 64 + lane] =
        make_float4(W1[lane], W1[lane + 64], W2[lane], W2[lane + 64]);
}

__global__ void k_embed(const int* __restrict__ an, const float* __restrict__ emb,
                        const float* __restrict__ W, const float* __restrict__ b,
                        float* __restrict__ x) {
    int c = threadIdx.x & 63, nl = threadIdx.x >> 6;
    int n = blockIdx.x * 4 + nl;
    if (n >= NN) return;
    const float* e = emb + (size_t)an[n] * 92;
    float acc = b[c];
#pragma unroll 4
    for (int k = 0; k < 92; k++) acc += e[k] * W[k * 64 + c];
    x[(size_t)n * 64 + c] = acc;
}

__global__ void k_hist(const int* __restrict__ dst, int* __restrict__ counts) {
    int e = blockIdx.x * 256 + threadIdx.x;
    if (e < EE) atomicAdd(&counts[dst[e]], 1);
}

__global__ void k_scan(const int* __restrict__ counts, int* __restrict__ rp) {
    __shared__ int buf[1024];
    __shared__ int carry;
    int tid = threadIdx.x;
    if (tid == 0) { carry = 0; rp[0] = 0; }
    __syncthreads();
    for (int base = 0; base < NN; base += 1024) {
        int i = base + tid;
        int val = (i < NN) ? counts[i] : 0;
        buf[tid] = val;
        __syncthreads();
        for (int off = 1; off < 1024; off <<= 1) {
            int t = (tid >= off) ? buf[tid - off] : 0;
            __syncthreads();
            buf[tid] += t;
            __syncthreads();
        }
        if (i < NN) rp[i + 1] = carry + buf[tid];
        __syncthreads();
        if (tid == 0) carry += buf[1023];
        __syncthreads();
    }
}

__global__ void k_scatter(const int* __restrict__ dst, const int* __restrict__ rp,
                          int* __restrict__ cursor, int* __restrict__ perm) {
    int e = blockIdx.x * 256 + threadIdx.x;
    if (e < EE) {
        int d = dst[e];
        int p = atomicAdd(&cursor[d], 1);
        perm[rp[d] + p] = e;
    }
}

// packed edge record in perm order: (src<<17) | (j<<5) | f5
__global__ void k_edges(const int* __restrict__ perm, const int* __restrict__ src,
                        const float* __restrict__ dist, unsigned* __restrict__ ej) {
    int idx = blockIdx.x * 256 + threadIdx.x;
    if (idx >= EE) return;
    int e = perm[idx];
    float t = dist[e] * (4095.0f / 6.0f);
    int j = (int)t;
    if (j > TS - 2) j = TS - 2;
    float f = t - (float)j;
    f = fminf(fmaxf(f, 0.0f), 1.0f);
    unsigned f5 = (unsigned)(f * 32.0f);
    if (f5 > 31u) f5 = 31u;
    ej[idx] = ((unsigned)src[e] << 17) | ((unsigned)j << 5) | f5;
}

// u,v: 4 nodes per wave, Wp float4 loads, readlane broadcast
__global__ void __launch_bounds__(256) k_uv(const float* __restrict__ x,
                                            const float4* __restrict__ Wp,
                                            __half2* __restrict__ up, __half2* __restrict__ vp) {
    int lane = threadIdx.x & 63;
    int wv = __builtin_amdgcn_readfirstlane(threadIdx.x >> 6);
    int n0 = (blockIdx.x * 4 + wv) * 4;
    float xa = x[(size_t)(n0 + 0) * 64 + lane];
    float xb = x[(size_t)(n0 + 1) * 64 + lane];
    float xc = x[(size_t)(n0 + 2) * 64 + lane];
    float xd = x[(size_t)(n0 + 3) * 64 + lane];
    float2 ua = {0, 0}, ub = {0, 0}, uc = {0, 0}, ud = {0, 0};
    float2 va = {0, 0}, vb = {0, 0}, vc = {0, 0}, vd = {0, 0};
#pragma unroll 8
    for (int k = 0; k < 64; k++) {
        float4 w = Wp[k * 64 + lane];
        float ka = __uint_as_float(__builtin_amdgcn_readlane(__float_as_uint(xa), k));
        float kb = __uint_as_float(__builtin_amdgcn_readlane(__float_as_uint(xb), k));
        float kc = __uint_as_float(__builtin_amdgcn_readlane(__float_as_uint(xc), k));
        float kd = __uint_as_float(__builtin_amdgcn_readlane(__float_as_uint(xd), k));
        ua.x += ka * w.x; ua.y += ka * w.y; va.x += ka * w.z; va.y += ka * w.w;
        ub.x += kb * w.x; ub.y += kb * w.y; vb.x += kb * w.z; vb.y += kb * w.w;
        uc.x += kc * w.x; uc.y += kc * w.y; vc.x += kc * w.z; vc.y += kc * w.w;
        ud.x += kd * w.x; ud.y += kd * w.y; vd.x += kd * w.z; vd.y += kd * w.w;
    }
    up[(size_t)(n0 + 0) * 64 + lane] = __floats2half2_rn(ua.x, ua.y);
    up[(size_t)(n0 + 1) * 64 + lane] = __floats2half2_rn(ub.x, ub.y);
    up[(size_t)(n0 + 2) * 64 + lane] = __floats2half2_rn(uc.x, uc.y);
    up[(size_t)(n0 + 3) * 64 + lane] = __floats2half2_rn(ud.x, ud.y);
    vp[(size_t)(n0 + 0) * 64 + lane] = __floats2half2_rn(va.x, va.y);
    vp[(size_t)(n0 + 1) * 64 + lane] = __floats2half2_rn(vb.x, vb.y);
    vp[(size_t)(n0 + 2) * 64 + lane] = __floats2half2_rn(vc.x, vc.y);
    vp[(size_t)(n0 + 3) * 64 + lane] = __floats2half2_rn(vd.x, vd.y);
}

// pass A: BN stats; node-strided waves, scalar edge records, 8-deep pipeline
__global__ void __launch_bounds__(256) k_stats(
    const __half2* __restrict__ up, const __half2* __restrict__ vp,
    const uint2* __restrict__ Tq, const unsigned* __restrict__ ej,
    const int* __restrict__ rp, float* __restrict__ sums) {
    int lane = threadIdx.x & 63;
    int wv = __builtin_amdgcn_readfirstlane(threadIdx.x >> 6);
    float sx = 0.f, sy = 0.f, qx = 0.f, qy = 0.f;
    for (int i = blockIdx.x * 4 + wv; i < NN; i += gridDim.x * 4) {
        float2 uu = __half22float2(up[(size_t)i * 64 + lane]);
        int rs = rp[i], re = rp[i + 1];
        int idx = rs;
        for (; idx + 8 <= re; idx += 8) {
            unsigned e[8];
#pragma unroll
            for (int t = 0; t < 8; t++) e[t] = ej[idx + t];
            __half2 vh[8]; uint2 th[8];
#pragma unroll
            for (int t = 0; t < 8; t++) {
                vh[t] = vp[(size_t)(e[t] >> 17) * 64 + lane];
                th[t] = Tq[(size_t)((e[t] >> 5) & 0xFFFu) * 64 + lane];
            }
#pragma unroll
            for (int t = 0; t < 8; t++) {
                float f = ((float)(e[t] & 31u) + 0.5f) * (1.0f / 32.0f);
                float2 vv = __half22float2(vh[t]);
                float2 t0 = __half22float2(*(const __half2*)&th[t].x);
                float2 t1 = __half22float2(*(const __half2*)&th[t].y);
                float z0 = uu.x + vv.x + t0.x + (t1.x - t0.x) * f;
                float z1 = uu.y + vv.y + t0.y + (t1.y - t0.y) * f;
                sx += z0; qx += z0 * z0;
                sy += z1; qy += z1 * z1;
            }
        }
        for (; idx < re; ++idx) {
            unsigned e = ej[idx];
            float f = ((float)(e & 31u) + 0.5f) * (1.0f / 32.0f);
            float2 vv = __half22float2(vp[(size_t)(e >> 17) * 64 + lane]);
            uint2 tq = Tq[(size_t)((e >> 5) & 0xFFFu) * 64 + lane];
            float2 t0 = __half22float2(*(const __half2*)&tq.x);
            float2 t1 = __half22float2(*(const __half2*)&tq.y);
            float z0 = uu.x + vv.x + t0.x + (t1.x - t0.x) * f;
            float z1 = uu.y + vv.y + t0.y + (t1.y - t0.y) * f;
            sx += z0; qx += z0 * z0;
            sy += z1; qy += z1 * z1;
        }
    }
    __shared__ float red[4][64][4];
    red[wv][lane][0] = sx; red[wv][lane][1] = sy;
    red[wv][lane][2] = qx; red[wv][lane][3] = qy;
    __syncthreads();
    if (wv == 0) {
        for (int r = 1; r < 4; r++) {
            sx += red[r][lane][0]; sy += red[r][lane][1];
            qx += red[r][lane][2]; qy += red[r][lane][3];
        }
        atomicAdd(&sums[lane], sx);
        atomicAdd(&sums[lane + 64], sy);
        atomicAdd(&sums[128 + lane], qx);
        atomicAdd(&sums[192 + lane], qy);
    }
}

// pass B: wave-per-node; inline BN finalize from sums; 8-deep pipeline;
// LN + residual + softplus epilogue in shuffles
__global__ void __launch_bounds__(256) k_agg(
    const __half2* __restrict__ up, const __half2* __restrict__ vp,
    const uint2* __restrict__ Tq, const unsigned* __restrict__ ej,
    const int* __restrict__ rp, const float* __restrict__ sums,
    const float* __restrict__ bng, const float* __restrict__ bnb,
    const float* __restrict__ lng, const float* __restrict__ lnb,
    int l, const float* __restrict__ xin, float* __restrict__ xout) {
    int lane = threadIdx.x & 63;
    int wv = __builtin_amdgcn_readfirstlane(threadIdx.x >> 6);
    int i = blockIdx.x * 4 + wv;
    // inline BN fold
    float mu1 = sums[lane] * (1.0f / EE);
    float var1 = sums[128 + lane] * (1.0f / EE) - mu1 * mu1;
    float A1 = rsqrtf(var1 + EPS) * bng[l * 128 + lane];
    float B1 = bnb[l * 128 + lane] - mu1 * A1;
    float mu2 = sums[64 + lane] * (1.0f / EE);
    float var2 = sums[192 + lane] * (1.0f / EE) - mu2 * mu2;
    float A2 = rsqrtf(var2 + EPS) * bng[l * 128 + 64 + lane];
    float B2 = bnb[l * 128 + 64 + lane] - mu2 * A2;

    float2 uu = __half22float2(up[(size_t)i * 64 + lane]);
    float xr = xin[(size_t)i * 64 + lane];
    float acc = 0.f;
    int rs = rp[i], re = rp[i + 1];
    int idx = rs;
    for (; idx + 8 <= re; idx += 8) {
        unsigned e[8];
#pragma unroll
        for (int t = 0; t < 8; t++) e[t] = ej[idx + t];
        __half2 vh[8]; uint2 th[8];
#pragma unroll
        for (int t = 0; t < 8; t++) {
            vh[t] = vp[(size_t)(e[t] >> 17) * 64 + lane];
            th[t] = Tq[(size_t)((e[t] >> 5) & 0xFFFu) * 64 + lane];
        }
#pragma unroll
        for (int t = 0; t < 8; t++) {
            float f = ((float)(e[t] & 31u) + 0.5f) * (1.0f / 32.0f);
            float2 vv = __half22float2(vh[t]);
            float2 t0 = __half22float2(*(const __half2*)&th[t].x);
            float2 t1 = __half22float2(*(const __half2*)&th[t].y);
            float z0 = (uu.x + vv.x + t0.x + (t1.x - t0.x) * f) * A1 + B1;
            float z1 = (uu.y + vv.y + t0.y + (t1.y - t0.y) * f) * A2 + B2;
            acc += sigmoid_fast(z0) * softplus_fast(z1);
        }
    }
    for (; idx < re; ++idx) {
        unsigned e = ej[idx];
        float f = ((float)(e & 31u) + 0.5f) * (1.0f / 32.0f);
        float2 vv = __half22float2(vp[(size_t)(e >> 17) * 64 + lane]);
        uint2 tq = Tq[(size_t)((e >> 5) & 0xFFFu) * 64 + lane];
        float2 t0 = __half22float2(*(const __half2*)&tq.x);
        float2 t1 = __half22float2(*(const __half2*)&tq.y);
        float z0 = (uu.x + vv.x + t0.x + (t1.x - t0.x) * f) * A1 + B1;
        float z1 = (uu.y + vv.y + t0.y + (t1.y - t0.y) * f) * A2 + B2;
        acc += sigmoid_fast(z0) * softplus_fast(z1);
    }
    float s = acc;
#pragma unroll
    for (int off = 32; off; off >>= 1) s += __shfl_xor(s, off, 64);
    float mean = s * (1.0f / 64.0f);
    float e0v = acc - mean;
    float vv2 = e0v * e0v;
#pragma unroll
    for (int off = 32; off; off >>= 1) vv2 += __shfl_xor(vv2, off, 64);
    float var = vv2 * (1.0f / 64.0f);
    float h = e0v * rsqrtf(var + EPS) * lng[l * 64 + lane] + lnb[l * 64 + lane];
    xout[(size_t)i * 64 + lane] = softplus_ref(h + xr);
}

// batch sorted -> graph row pointers by binary search
__global__ void k_gp(const int* __restrict__ batch, int* __restrict__ gp) {
    int g = threadIdx.x;
    if (g > GG) return;
    int lo = 0, hi = NN;
    while (lo < hi) {
        int mid = (lo + hi) >> 1;
        if (batch[mid] < g) lo = mid + 1; else hi = mid;
    }
    gp[g] = lo;
}

// atomic-free segmented mean-pool
__global__ void k_pool2(const float* __restrict__ x, const int* __restrict__ gp,
                        float* __restrict__ mols) {
    int g = blockIdx.x;
    int lane = threadIdx.x & 63, slot = threadIdx.x >> 6;
    int s0 = gp[g], s1 = gp[g + 1];
    float acc = 0.f;
    for (int n = s0 + slot; n < s1; n += 4) acc += x[(size_t)n * 64 + lane];
    __shared__ float red[4][64];
    red[slot][lane] = acc;
    __syncthreads();
    if (slot == 0) {
        float a = red[0][lane] + red[1][lane] + red[2][lane] + red[3][lane];
        float cc = fmaxf((float)(s1 - s0), 1.0f);
        mols[g * 64 + lane] = a / cc;
    }
}

__global__ void k_mlp(const float* __restrict__ mols,
                      const float* __restrict__ fc1W, const float* __restrict__ fc1b,
                      const float* __restrict__ fcsW, const float* __restrict__ fcsb,
                      const float* __restrict__ outW, const float* __restrict__ outb,
                      float* __restrict__ y) {
    int g = blockIdx.x, t = threadIdx.x; // 128 threads
    __shared__ float m[64];
    __shared__ float h[128];
    __shared__ float rbuf[128];
    if (t < 64) m[t] = mols[g * 64 + t];
    __syncthreads();
    float a = fc1b[t];
#pragma unroll 4
    for (int k = 0; k < 64; k++) a += m[k] * fc1W[k * 128 + t];
    h[t] = softplus_ref(a);
    __syncthreads();
    for (int i = 0; i < 3; i++) {
        float b = fcsb[i * 128 + t];
#pragma unroll 4
        for (int k = 0; k < 128; k++) b += h[k] * fcsW[((size_t)i * 128 + k) * 128 + t];
        __syncthreads();
        h[t] = softplus_ref(b);
        __syncthreads();
    }
    rbuf[t] = h[t] * outW[t];
    __syncthreads();
    if (t < 64) {
        float s2 = rbuf[t] + rbuf[t + 64];
#pragma unroll
        for (int off = 32; off; off >>= 1) s2 += __shfl_xor(s2, off, 64);
        if (t == 0) y[g] = s2 + outb[0];
    }
}

extern "C" void kernel_launch(void* const* d_in, const int* in_sizes, int n_in,
                              void* d_out, int out_size, void* d_ws, size_t ws_size,
                              hipStream_t stream) {
    const int*   an    = (const int*)d_in[0];
    const int*   nbr   = (const int*)d_in[1];
    const float* dist  = (const float*)d_in[2];
    const int*   batch = (const int*)d_in[3];
    const float* emb   = (const float*)d_in[4];
    const float* nucW  = (const float*)d_in[5];
    const float* nucB  = (const float*)d_in[6];
    const float* convW = (const float*)d_in[7];
    const float* convB = (const float*)d_in[8];
    const float* bng   = (const float*)d_in[9];
    const float* bnb   = (const float*)d_in[10];
    const float* lng   = (const float*)d_in[11];
    const float* lnb   = (const float*)d_in[12];
    const float* fc1W  = (const float*)d_in[13];
    const float* fc1b  = (const float*)d_in[14];
    const float* fcsW  = (const float*)d_in[15];
    const float* fcsb  = (const float*)d_in[16];
    const float* outW  = (const float*)d_in[17];
    const float* outb  = (const float*)d_in[18];
    const int* srcI = nbr;
    const int* dstI = nbr + EE;

    char* base = (char*)d_ws;
    size_t off = 0;
    auto alloc = [&](size_t b) { size_t r = off; off += (b + 255) & ~(size_t)255; return r; };
    float*    gtab   = (float*)(base + alloc((size_t)TS * 100 * 4));
    __half2*  Tall   = (__half2*)(base + alloc((size_t)6 * TS * 64 * 4));
    uint2*    Tq     = (uint2*)(base + alloc((size_t)6 * TS * 64 * 8));
    float4*   Wp     = (float4*)(base + alloc((size_t)6 * 64 * 64 * 16));
    float*    x0     = (float*)(base + alloc((size_t)NN * 64 * 4));
    float*    x1     = (float*)(base + alloc((size_t)NN * 64 * 4));
    __half2*  up     = (__half2*)(base + alloc((size_t)NN * 64 * 4));
    __half2*  vp     = (__half2*)(base + alloc((size_t)NN * 64 * 4));
    float*    sums6  = (float*)(base + alloc((size_t)6 * 256 * 4));
    int*      counts = (int*)(base + alloc((size_t)NN * 4));
    int*      cursor = (int*)(base + alloc((size_t)NN * 4));
    int*      rp     = (int*)(base + alloc((size_t)(NN + 1) * 4));
    int*      perm   = (int*)(base + alloc((size_t)EE * 4));
    unsigned* ej     = (unsigned*)(base + alloc((size_t)EE * 4));
    float*    mols   = (float*)(base + alloc((size_t)GG * 64 * 4));
    int*      gp     = (int*)(base + alloc((size_t)(GG + 1) * 4));

    hipMemsetAsync(counts, 0, (size_t)NN * 4, stream);
    hipMemsetAsync(cursor, 0, (size_t)NN * 4, stream);
    hipMemsetAsync(sums6, 0, (size_t)6 * 256 * 4, stream);

    k_gtab<<<(TS * 100 + 255) / 256, 256, 0, stream>>>(gtab);
    k_build_T<<<dim3(TS, 6), 64, 0, stream>>>(gtab, convW, convB, Tall);
    k_build_Tq<<<dim3(TS, 6), 64, 0, stream>>>(Tall, Tq);
    k_prepW<<<dim3(64, 6), 64, 0, stream>>>(convW, Wp);
    k_embed<<<(NN + 3) / 4, 256, 0, stream>>>(an, emb, nucW, nucB, x0);
    k_hist<<<(EE + 255) / 256, 256, 0, stream>>>(dstI, counts);
    k_scan<<<1, 1024, 0, stream>>>(counts, rp);
    k_scatter<<<(EE + 255) / 256, 256, 0, stream>>>(dstI, rp, cursor, perm);
    k_edges<<<(EE + 255) / 256, 256, 0, stream>>>(perm, srcI, dist, ej);
    k_gp<<<1, 128, 0, stream>>>(batch, gp);

    float* xin = x0;
    float* xout = x1;
    for (int l = 0; l < 6; l++) {
        k_uv<<<NN / 16, 256, 0, stream>>>(xin, Wp + (size_t)l * 64 * 64, up, vp);
        const uint2* Tql = Tq + (size_t)l * TS * 64;
        float* sums = sums6 + (size_t)l * 256;
        k_stats<<<2048, 256, 0, stream>>>(up, vp, Tql, ej, rp, sums);
        k_agg<<<NN / 4, 256, 0, stream>>>(up, vp, Tql, ej, rp, sums,
                                          bng, bnb, lng, lnb, l, xin, xout);
        float* tmp = xin; xin = xout; xout = tmp;
    }
    k_pool2<<<GG, 256, 0, stream>>>(xin, gp, mols);
    k_mlp<<<GG, 128, 0, stream>>>(mols, fc1W, fc1b, fcsW, fcsb, outW, outb, (float*)d_out);
}